// Round 1
// baseline (1508.586 us; speedup 1.0000x reference)
//
#include <hip/hip_runtime.h>

#define VOCAB 50000
#define EMB   128
#define CTX   128
#define NH    4
#define HSZ   32
#define NL    4
#define FFD   512
#define BATCH 32
#define MROWS 4096   // BATCH*CTX

typedef float  f32x4  __attribute__((ext_vector_type(4)));
typedef __bf16 bf16x8 __attribute__((ext_vector_type(8)));

__device__ inline unsigned short f2bf(float f) {
    unsigned int u = __builtin_bit_cast(unsigned int, f);
    u += 0x7FFFu + ((u >> 16) & 1u);          // round-to-nearest-even
    return (unsigned short)(u >> 16);
}

__device__ inline float wave_red_sum(float v) {
    #pragma unroll
    for (int off = 32; off; off >>= 1) v += __shfl_xor(v, off);
    return v;
}

// ---------------------------------------------------------------- Wf -> bf16, transposed (V x E)
__global__ __launch_bounds__(256) void k_wf_t(const float* __restrict__ Wf,
                                              unsigned short* __restrict__ Wft) {
    int n = blockIdx.x * 256 + threadIdx.x;
    if (n >= VOCAB) return;
    for (int k0 = 0; k0 < EMB; k0 += 8) {
        uint4 val;
        val.x = (unsigned)f2bf(Wf[(size_t)(k0+0)*VOCAB + n]) | ((unsigned)f2bf(Wf[(size_t)(k0+1)*VOCAB + n]) << 16);
        val.y = (unsigned)f2bf(Wf[(size_t)(k0+2)*VOCAB + n]) | ((unsigned)f2bf(Wf[(size_t)(k0+3)*VOCAB + n]) << 16);
        val.z = (unsigned)f2bf(Wf[(size_t)(k0+4)*VOCAB + n]) | ((unsigned)f2bf(Wf[(size_t)(k0+5)*VOCAB + n]) << 16);
        val.w = (unsigned)f2bf(Wf[(size_t)(k0+6)*VOCAB + n]) | ((unsigned)f2bf(Wf[(size_t)(k0+7)*VOCAB + n]) << 16);
        *(uint4*)(Wft + (size_t)n*EMB + k0) = val;
    }
}

// ---------------------------------------------------------------- embedding gather
__global__ void k_embed(const int* __restrict__ idx, const float* __restrict__ tok,
                        const float* __restrict__ pos, float* __restrict__ x) {
    int r = blockIdx.x, e = threadIdx.x;
    int i = idx[r];
    x[(size_t)r*EMB + e] = tok[(size_t)i*EMB + e] + pos[(size_t)i*EMB + e];
}

// LN (unbiased, ddof=1) of a 16-row tile into transposed LDS ht[e*20 + row]
__device__ inline void ln_tile_unbiased(const float* __restrict__ x, int rbase,
                                        const float* __restrict__ g, const float* __restrict__ bb,
                                        float* ht, int tid) {
    int wid = tid >> 6, lane = tid & 63;
    #pragma unroll
    for (int q = 0; q < 4; q++) {
        int row = wid*4 + q;
        const float* xr = x + (size_t)(rbase + row)*EMB;
        float v0 = xr[lane], v1 = xr[lane + 64];
        float s = wave_red_sum(v0 + v1);
        float mean = s * (1.f/128.f);
        float d0 = v0 - mean, d1 = v1 - mean;
        float vs = wave_red_sum(d0*d0 + d1*d1);
        float rstd = rsqrtf(vs * (1.f/127.f) + 1e-5f);
        ht[lane*20 + row]      = d0*rstd*g[lane]    + bb[lane];
        ht[(lane+64)*20 + row] = d1*rstd*g[lane+64] + bb[lane+64];
    }
}

// ---------------------------------------------------------------- LN1 + K/V projection
__global__ __launch_bounds__(256) void k_kvproj(const float* __restrict__ x,
        const float* __restrict__ Wk_l, const float* __restrict__ bk_l,
        const float* __restrict__ Wv_l, const float* __restrict__ bv_l,
        const float* __restrict__ g, const float* __restrict__ bb,
        float* __restrict__ kws, float* __restrict__ vws) {
    __shared__ __align__(16) float ht[EMB*20];
    int tid = threadIdx.x;
    int rbase = blockIdx.x * 16;
    ln_tile_unbiased(x, rbase, g, bb, ht, tid);
    __syncthreads();
    int col = tid & 127, rg = tid >> 7;
    int hc = col >> 5, f = col & 31;
    float acck[8] = {}, accv[8] = {};
    const float* wk = Wk_l + hc*4096 + f;
    const float* wv = Wv_l + hc*4096 + f;
    for (int e = 0; e < EMB; e++) {
        float hv[8];
        *(float4*)hv     = *(float4*)&ht[e*20 + rg*8];
        *(float4*)(hv+4) = *(float4*)&ht[e*20 + rg*8 + 4];
        float a = wk[e*32], b = wv[e*32];
        #pragma unroll
        for (int i = 0; i < 8; i++) { acck[i] += hv[i]*a; accv[i] += hv[i]*b; }
    }
    float kb = bk_l[hc*32 + f], vb = bv_l[hc*32 + f];
    #pragma unroll
    for (int i = 0; i < 8; i++) {
        int R = rbase + rg*8 + i;
        int addr = (((R >> 7)*NH + hc)*CTX + (R & 127))*HSZ + f;
        kws[addr] = acck[i] + kb;
        vws[addr] = accv[i] + vb;
    }
}

// ---------------------------------------------------------------- attention (scores use k@k^T — source bug preserved)
__global__ __launch_bounds__(256) void k_attn(const float* __restrict__ kws,
                                              const float* __restrict__ vws,
                                              float* __restrict__ ows) {
    __shared__ __align__(16) float kl[CTX*36];
    __shared__ __align__(16) float vl[CTX*36];
    __shared__ float P[32*132];
    __shared__ float invr[32];
    int tid = threadIdx.x;
    int bh = blockIdx.x >> 2, qc = blockIdx.x & 3;
    const float* kb = kws + (size_t)bh*CTX*HSZ;
    const float* vb = vws + (size_t)bh*CTX*HSZ;
    #pragma unroll
    for (int it = 0; it < 4; it++) {
        int idx = it*1024 + tid*4;
        int j = idx >> 5, f0 = idx & 31;
        *(float4*)&kl[j*36 + f0] = *(const float4*)&kb[idx];
        *(float4*)&vl[j*36 + f0] = *(const float4*)&vb[idx];
    }
    __syncthreads();
    int cq = tid >> 3, jl = tid & 7;
    int cg = qc*32 + cq;
    float kc[HSZ];
    #pragma unroll
    for (int f = 0; f < HSZ; f++) kc[f] = kl[cg*36 + f];
    const float scale = 0.08838834764831843f;   // 1/sqrt(C)
    float mx = -1e30f;
    float sv[16];
    for (int jj = 0; jj < 16; jj++) {
        int j = jl + jj*8;
        float s = 0.f;
        #pragma unroll
        for (int f = 0; f < HSZ; f++) s += kc[f]*kl[j*36 + f];
        s *= scale;
        if (j > cg) s = -1e30f;
        sv[jj] = s;
        mx = fmaxf(mx, s);
    }
    mx = fmaxf(mx, __shfl_xor(mx, 1));
    mx = fmaxf(mx, __shfl_xor(mx, 2));
    mx = fmaxf(mx, __shfl_xor(mx, 4));
    float sum = 0.f;
    for (int jj = 0; jj < 16; jj++) {
        float p = __expf(sv[jj] - mx);
        P[cq*132 + jl + jj*8] = p;
        sum += p;
    }
    sum += __shfl_xor(sum, 1);
    sum += __shfl_xor(sum, 2);
    sum += __shfl_xor(sum, 4);
    if (jl == 0) invr[cq] = 1.f / sum;
    __syncthreads();
    int f0 = (tid & 7)*4;
    float ax = 0, ay = 0, az = 0, aw = 0;
    for (int j = 0; j <= cg; j++) {
        float p = P[cq*132 + j];
        float4 vv = *(float4*)&vl[j*36 + f0];
        ax += p*vv.x; ay += p*vv.y; az += p*vv.z; aw += p*vv.w;
    }
    float inv = invr[cq];
    int b = bh >> 2, hh = bh & 3;
    float4 o; o.x = ax*inv; o.y = ay*inv; o.z = az*inv; o.w = aw*inv;
    *(float4*)&ows[(size_t)(b*CTX + cg)*EMB + hh*HSZ + f0] = o;
}

// ---------------------------------------------------------------- x += o @ Wo + bo
__global__ __launch_bounds__(256) void k_wo(const float* __restrict__ ows,
        const float* __restrict__ Wo_l, const float* __restrict__ bo_l,
        float* __restrict__ x) {
    __shared__ __align__(16) float ot[EMB*20];
    int tid = threadIdx.x;
    int rbase = blockIdx.x * 16;
    int r = tid & 15, qd = tid >> 4;
    #pragma unroll
    for (int it = 0; it < 2; it++) {
        int e0 = qd*4 + it*64;
        float4 v = *(const float4*)&ows[(size_t)(rbase + r)*EMB + e0];
        ot[(e0+0)*20 + r] = v.x; ot[(e0+1)*20 + r] = v.y;
        ot[(e0+2)*20 + r] = v.z; ot[(e0+3)*20 + r] = v.w;
    }
    __syncthreads();
    int col = tid & 127, rg = tid >> 7;
    float acc[8] = {};
    for (int e = 0; e < EMB; e++) {
        float hv[8];
        *(float4*)hv     = *(float4*)&ot[e*20 + rg*8];
        *(float4*)(hv+4) = *(float4*)&ot[e*20 + rg*8 + 4];
        float w = Wo_l[e*EMB + col];
        #pragma unroll
        for (int i = 0; i < 8; i++) acc[i] += hv[i]*w;
    }
    float bo = bo_l[col];
    #pragma unroll
    for (int i = 0; i < 8; i++) {
        int R = rbase + rg*8 + i;
        x[(size_t)R*EMB + col] += acc[i] + bo;
    }
}

// ---------------------------------------------------------------- LN2 + FFN up + ReLU
__global__ __launch_bounds__(256) void k_ffn1(const float* __restrict__ x,
        const float* __restrict__ W1_l, const float* __restrict__ b1_l,
        const float* __restrict__ g, const float* __restrict__ bb,
        float* __restrict__ fws) {
    __shared__ __align__(16) float ht[EMB*20];
    int tid = threadIdx.x;
    int rbase = blockIdx.x * 16;
    ln_tile_unbiased(x, rbase, g, bb, ht, tid);
    __syncthreads();
    int col = tid & 127, rg = tid >> 7;
    float acc[4][8] = {};
    for (int e = 0; e < EMB; e++) {
        float hv[8];
        *(float4*)hv     = *(float4*)&ht[e*20 + rg*8];
        *(float4*)(hv+4) = *(float4*)&ht[e*20 + rg*8 + 4];
        const float* wrow = W1_l + (size_t)e*FFD + col;
        #pragma unroll
        for (int cc = 0; cc < 4; cc++) {
            float w = wrow[cc*128];
            #pragma unroll
            for (int i = 0; i < 8; i++) acc[cc][i] += hv[i]*w;
        }
    }
    #pragma unroll
    for (int cc = 0; cc < 4; cc++) {
        float bv = b1_l[col + cc*128];
        #pragma unroll
        for (int i = 0; i < 8; i++) {
            int R = rbase + rg*8 + i;
            fws[(size_t)R*FFD + col + cc*128] = fmaxf(acc[cc][i] + bv, 0.f);
        }
    }
}

// ---------------------------------------------------------------- x += f @ W2 + b2
__global__ __launch_bounds__(256) void k_ffn2(const float* __restrict__ fws,
        const float* __restrict__ W2_l, const float* __restrict__ b2_l,
        float* __restrict__ x) {
    __shared__ __align__(16) float ft[FFD*20];
    int tid = threadIdx.x;
    int rbase = blockIdx.x * 16;
    int r = tid & 15, qd = tid >> 4;
    #pragma unroll
    for (int it = 0; it < 8; it++) {
        int e0 = qd*4 + it*64;
        float4 v = *(const float4*)&fws[(size_t)(rbase + r)*FFD + e0];
        ft[(e0+0)*20 + r] = v.x; ft[(e0+1)*20 + r] = v.y;
        ft[(e0+2)*20 + r] = v.z; ft[(e0+3)*20 + r] = v.w;
    }
    __syncthreads();
    int col = tid & 127, rg = tid >> 7;
    float acc[8] = {};
    for (int e = 0; e < FFD; e++) {
        float hv[8];
        *(float4*)hv     = *(float4*)&ft[e*20 + rg*8];
        *(float4*)(hv+4) = *(float4*)&ft[e*20 + rg*8 + 4];
        float w = W2_l[(size_t)e*EMB + col];
        #pragma unroll
        for (int i = 0; i < 8; i++) acc[i] += hv[i]*w;
    }
    float bv = b2_l[col];
    #pragma unroll
    for (int i = 0; i < 8; i++) {
        int R = rbase + rg*8 + i;
        x[(size_t)R*EMB + col] += acc[i] + bv;
    }
}

// ---------------------------------------------------------------- final LN (biased) -> bf16
__global__ void k_lnf(const float* __restrict__ x, const float* __restrict__ g,
                      const float* __restrict__ bb, unsigned short* __restrict__ xbf) {
    int r = blockIdx.x, lane = threadIdx.x;   // 64 threads
    const float* xr = x + (size_t)r*EMB;
    float v0 = xr[lane], v1 = xr[lane + 64];
    float s = wave_red_sum(v0 + v1);
    float mean = s * (1.f/128.f);
    float d0 = v0 - mean, d1 = v1 - mean;
    float vs = wave_red_sum(d0*d0 + d1*d1);
    float rstd = rsqrtf(vs * (1.f/128.f) + 1e-5f);
    xbf[(size_t)r*EMB + lane]      = f2bf(d0*rstd*g[lane]    + bb[lane]);
    xbf[(size_t)r*EMB + lane + 64] = f2bf(d1*rstd*g[lane+64] + bb[lane+64]);
}

// ---------------------------------------------------------------- final GEMM: out = xbf @ Wft^T + bf  (M=4096,N=50000,K=128)
__global__ __launch_bounds__(256) void k_final(const unsigned short* __restrict__ xbf,
        const unsigned short* __restrict__ Wft, const float* __restrict__ bfv,
        float* __restrict__ out) {
    __shared__ __align__(16) unsigned short Bsm[128*136];   // [n][k], +8 bf16 pad
    int tid = threadIdx.x;
    int nbase = blockIdx.x * 128;
    int mbase = blockIdx.y * 128;
    // stage B tile (one 256B row per wave-instr: 2-way bank conflicts only)
    const unsigned* src = (const unsigned*)Wft;
    unsigned* dst = (unsigned*)Bsm;
    for (int it = 0; it < 32; it++) {
        int u = it*256 + tid;
        int n = u >> 6, c4 = u & 63;
        int ng = nbase + n;
        unsigned val = (ng < VOCAB) ? src[(size_t)ng*64 + c4] : 0u;
        dst[n*68 + c4] = val;
    }
    int wid = tid >> 6, lane = tid & 63;
    int lm = lane & 15, quad = lane >> 4;
    int wr = (wid >> 1)*64, wc = (wid & 1)*64;
    // A fragments straight from global (L2-hot, 16 rows x 64B per instr = fully coalesced)
    bf16x8 a[4][4];
    const unsigned short* ab = xbf + (size_t)(mbase + wr)*EMB;
    #pragma unroll
    for (int ms = 0; ms < 4; ms++)
        #pragma unroll
        for (int ks = 0; ks < 4; ks++)
            a[ms][ks] = *(const bf16x8*)(ab + (ms*16 + lm)*EMB + ks*32 + quad*8);
    __syncthreads();
    f32x4 acc[4][4] = {};
    #pragma unroll
    for (int ns = 0; ns < 4; ns++) {
        const unsigned short* bb2 = Bsm + (wc + ns*16 + lm)*136 + quad*8;
        #pragma unroll
        for (int ks = 0; ks < 4; ks++) {
            bf16x8 bfr = *(const bf16x8*)(bb2 + ks*32);
            #pragma unroll
            for (int ms = 0; ms < 4; ms++)
                acc[ms][ns] = __builtin_amdgcn_mfma_f32_16x16x32_bf16(a[ms][ks], bfr, acc[ms][ns], 0, 0, 0);
        }
    }
    #pragma unroll
    for (int ns = 0; ns < 4; ns++) {
        int n = nbase + wc + ns*16 + lm;
        if (n < VOCAB) {
            float bias = bfv[n];
            #pragma unroll
            for (int ms = 0; ms < 4; ms++) {
                int m = mbase + wr + ms*16 + quad*4;
                float* orow = out + (size_t)m*VOCAB + n;
                #pragma unroll
                for (int rr = 0; rr < 4; rr++)
                    orow[(size_t)rr*VOCAB] = acc[ms][ns][rr] + bias;
            }
        }
    }
}

extern "C" void kernel_launch(void* const* d_in, const int* in_sizes, int n_in,
                              void* d_out, int out_size, void* d_ws, size_t ws_size,
                              hipStream_t stream) {
    const int*   idx  = (const int*)d_in[0];
    const float* tok  = (const float*)d_in[1];
    const float* pos  = (const float*)d_in[2];
    const float* Wk   = (const float*)d_in[3];
    const float* bk   = (const float*)d_in[4];
    const float* Wv   = (const float*)d_in[5];
    const float* bv   = (const float*)d_in[6];
    const float* Wo   = (const float*)d_in[7];
    const float* bo   = (const float*)d_in[8];
    const float* W1   = (const float*)d_in[9];
    const float* b1   = (const float*)d_in[10];
    const float* W2   = (const float*)d_in[11];
    const float* b2   = (const float*)d_in[12];
    const float* ln1g = (const float*)d_in[13];
    const float* ln1b = (const float*)d_in[14];
    const float* ln2g = (const float*)d_in[15];
    const float* ln2b = (const float*)d_in[16];
    const float* lnfg = (const float*)d_in[17];
    const float* lnfb = (const float*)d_in[18];
    const float* Wf   = (const float*)d_in[19];
    const float* bf   = (const float*)d_in[20];
    float* out = (float*)d_out;
    char* ws = (char*)d_ws;
    float* x   = (float*)(ws);                         // 2 MB
    float* kws = (float*)(ws + (2u<<20));              // 2 MB
    float* vws = (float*)(ws + (4u<<20));              // 2 MB
    float* ows = (float*)(ws + (6u<<20));              // 2 MB
    float* fws = (float*)(ws + (8u<<20));              // 8 MB
    unsigned short* xbf = (unsigned short*)(ws + (16u<<20));  // 1 MB
    unsigned short* wft = (unsigned short*)(ws + (18u<<20));  // 12.8 MB

    k_wf_t<<<196, 256, 0, stream>>>(Wf, wft);
    k_embed<<<4096, 128, 0, stream>>>(idx, tok, pos, x);
    for (int l = 0; l < NL; l++) {
        k_kvproj<<<256, 256, 0, stream>>>(x, Wk + l*16384, bk + l*128,
                                          Wv + l*16384, bv + l*128,
                                          ln1g + l*128, ln1b + l*128, kws, vws);
        k_attn<<<512, 256, 0, stream>>>(kws, vws, ows);
        k_wo<<<256, 256, 0, stream>>>(ows, Wo + l*16384, bo + l*128, x);
        k_ffn1<<<256, 256, 0, stream>>>(x, W1 + l*65536, b1 + l*512,
                                        ln2g + l*128, ln2b + l*128, fws);
        k_ffn2<<<256, 256, 0, stream>>>(fws, W2 + l*65536, b2 + l*128, x);
    }
    k_lnf<<<4096, 64, 0, stream>>>(x, lnfg, lnfb, xbf);
    k_final<<<dim3(391, 32), 256, 0, stream>>>(xbf, wft, bf, out);
}